// Round 2
// baseline (626.928 us; speedup 1.0000x reference)
//
#include <hip/hip_runtime.h>

#define NTOK 197
#define C 768
#define C3 2304
#define BM 128
#define BK 32
#define PK 40    // round-1 fallback LDS pitch
#define NT 13
#define CPAD 772   // cls LDS pitch (floats)
#define AWP 200    // a_weight LDS pitch (ushorts)
#define XS_PLANE 20447232   // 128*208*768 (ushorts per g-plane)

typedef __attribute__((ext_vector_type(4))) float f32x4;
typedef __attribute__((ext_vector_type(8))) short bf16x8;
typedef unsigned int u32;

__device__ __forceinline__ ushort f2bf(float f){
  uint u = __float_as_uint(f);
  u += 0x7fffu + ((u >> 16) & 1u);   // RNE
  return (ushort)(u >> 16);
}
__device__ __forceinline__ uint pack2(float a, float b){
  return (uint)f2bf(a) | ((uint)f2bf(b) << 16);
}
__device__ __forceinline__ float bfu2f(uint u){ return __uint_as_float(u << 16); }

// wave-uniform LDS dest + per-lane global src, 16B/lane
__device__ __forceinline__ void glds16(ushort* lds, const ushort* gsrc){
  __builtin_amdgcn_global_load_lds((const __attribute__((address_space(1))) u32*)gsrc,
                                   (__attribute__((address_space(3))) u32*)lds, 16, 0, 0);
}

// ---------------------------------------------------------------------------
// fp32 -> bf16 converter (grid-stride over float4 chunks)
// ---------------------------------------------------------------------------
__global__ void cvt_bf16(const float* __restrict__ in, ushort* __restrict__ outp, int n4)
{
  int stride = gridDim.x * blockDim.x;
  for (int i = blockIdx.x*blockDim.x + threadIdx.x; i < n4; i += stride){
    float4 v = reinterpret_cast<const float4*>(in)[i];
    ushort4 o;
    o.x = f2bf(v.x); o.y = f2bf(v.y); o.z = f2bf(v.z); o.w = f2bf(v.w);
    reinterpret_cast<ushort4*>(outp)[i] = o;
  }
}

// ---------------------------------------------------------------------------
// conv v2: coalesced LDS-staged a_weight (bf16), fp32 accumulation.
// grid (36 oc-chunks, 16 b), block 256 = 64 o x 4 k-parts.
// ---------------------------------------------------------------------------
__global__ __launch_bounds__(256)
void conv_scales2(const float* __restrict__ x, const ushort* __restrict__ awbf,
                  const float* __restrict__ ab, float* __restrict__ s_ws)
{
  __shared__ __align__(16) float  cls[10][CPAD];   // rows 0,9 zero pad
  __shared__ __align__(16) ushort awt[64*AWP];     // 64 o x 192 cols, pitch 200
  __shared__ float partial[64][4][9];
  const int oc = blockIdx.x, b = blockIdx.y, tid = threadIdx.x;

  // stage CLS rows (t' = -1..8)
  for (int task = tid; task < 1920; task += 256){
    int row = task / 192, c4 = task % 192;
    float4 v = {0.f,0.f,0.f,0.f};
    if (row >= 1 && row <= 8)
      v = *reinterpret_cast<const float4*>(x + (size_t)(b*8 + row - 1)*NTOK*C + c4*4);
    *reinterpret_cast<float4*>(&cls[row][c4*4]) = v;
  }

  const int o_l = tid >> 2, part = tid & 3;
  float acc[8];
  #pragma unroll
  for (int t=0;t<8;t++) acc[t]=0.f;

  for (int it = 0; it < 12; ++it){
    const int i0 = it*64;
    // stage awt: 64 rows x 24 chunks of 8 ushorts, coalesced
    #pragma unroll
    for (int j = 0; j < 6; ++j){
      int task = tid + j*256;            // 0..1535
      int r = task / 24, c8 = task % 24;
      uint4 v = *reinterpret_cast<const uint4*>(awbf + (size_t)(oc*64 + r)*C3 + i0*3 + c8*8);
      *reinterpret_cast<uint4*>(&awt[r*AWP + c8*8]) = v;
    }
    __syncthreads();   // first iter: also covers cls

    #pragma unroll
    for (int qq = 0; qq < 4; ++qq){
      const int i_loc = part*16 + qq*4;
      const int ib = i0 + i_loc;
      float4 cv[10];
      #pragma unroll
      for (int t=0;t<10;t++) cv[t] = *reinterpret_cast<const float4*>(&cls[t][ib]);
      float wv[4][3];
      #pragma unroll
      for (int e=0;e<4;e++){
        #pragma unroll
        for (int dk=0;dk<3;dk++)
          wv[e][dk] = bfu2f((uint)awt[o_l*AWP + (i_loc+e)*3 + dk]);
      }
      #pragma unroll
      for (int e=0;e<4;e++){
        #pragma unroll
        for (int dk=0;dk<3;dk++){
          const float wf = wv[e][dk];
          #pragma unroll
          for (int t=0;t<8;t++){
            const float* cp = reinterpret_cast<const float*>(&cv[t+dk]);
            acc[t] += wf * cp[e];
          }
        }
      }
    }
    __syncthreads();   // protect awt before next stage
  }

  #pragma unroll
  for (int t=0;t<8;t++) partial[o_l][part][t] = acc[t];
  __syncthreads();

  for (int idx = tid; idx < 512; idx += 256){
    int o = idx >> 3, t = idx & 7;
    float v = partial[o][0][t] + partial[o][1][t]
            + partial[o][2][t] + partial[o][3][t]
            + ab[oc*64 + o] + 1.0f;
    s_ws[(size_t)(b*8 + t)*C3 + oc*64 + o] = v;
  }
}

// ---------------------------------------------------------------------------
// scale_x: Xs[g][bt][n][k] = bf16( x[bt][n][k] * s[bt][g*768+k] ), n>=197 -> 0
// ---------------------------------------------------------------------------
__global__ __launch_bounds__(256)
void scale_x(const float* __restrict__ x, const float* __restrict__ s_ws,
             ushort* __restrict__ Xs)
{
  const int NCH = 128*208*96;
  int stride = gridDim.x * blockDim.x;
  for (int idx = blockIdx.x*blockDim.x + threadIdx.x; idx < NCH; idx += stride){
    int kc = idx % 96;
    int n  = (idx / 96) % 208;
    int bt = idx / (96*208);
    uint4 og[3];
    #pragma unroll
    for (int g=0; g<3; g++) og[g] = (uint4){0u,0u,0u,0u};
    if (n < NTOK){
      const float* xp = x + ((size_t)bt*NTOK + n)*C + kc*8;
      float4 xa = *reinterpret_cast<const float4*>(xp);
      float4 xb = *reinterpret_cast<const float4*>(xp+4);
      #pragma unroll
      for (int g=0; g<3; g++){
        const float* sp = s_ws + (size_t)bt*C3 + g*C + kc*8;
        float4 sa = *reinterpret_cast<const float4*>(sp);
        float4 sb = *reinterpret_cast<const float4*>(sp+4);
        og[g].x = pack2(xa.x*sa.x, xa.y*sa.y);
        og[g].y = pack2(xa.z*sa.z, xa.w*sa.w);
        og[g].z = pack2(xb.x*sb.x, xb.y*sb.y);
        og[g].w = pack2(xb.z*sb.z, xb.w*sb.w);
      }
    }
    size_t base = ((size_t)bt*208 + n)*C + kc*8;
    #pragma unroll
    for (int g=0; g<3; g++)
      *reinterpret_cast<uint4*>(Xs + (size_t)g*XS_PLANE + base) = og[g];
  }
}

// ---------------------------------------------------------------------------
// gemm2: pure bf16 GEMM per g: Out = W_g (768x768) x Xs_g^T (768 x 26624)
// m97 structure: 128x128 tile, BK=32, 4 waves x 4x4 frags, global_load_lds.
// ---------------------------------------------------------------------------
__global__ __launch_bounds__(256)
void gemm2(const ushort* __restrict__ wbf, const ushort* __restrict__ Xs,
           const float* __restrict__ s_ws, const float* __restrict__ bias,
           float* __restrict__ out)
{
  __shared__ __align__(16) ushort A_lds[128*32];
  __shared__ __align__(16) ushort B_lds[128*32];
  const int tn = blockIdx.x;      // 0..207
  const int tm = blockIdx.y;      // 0..5
  const int g  = blockIdx.z;      // 0..2
  const int tid = threadIdx.x, w = tid >> 6, lane = tid & 63;
  const int l15 = lane & 15, lq = lane >> 4;
  const int wm = w >> 1, wn = w & 1;

  const ushort* Ap = wbf + (size_t)g*C*C + (size_t)(tm*128)*C;
  const ushort* Bp = Xs  + (size_t)g*XS_PLANE + (size_t)(tn*128)*C;

  const int srow0 = w*32 + (lane >> 2);   // staging row, +16 for second issue
  const int scol  = (lane & 3)*8;

  f32x4 acc[4][4];
  #pragma unroll
  for (int i=0;i<4;i++)
    #pragma unroll
    for (int j=0;j<4;j++) acc[i][j] = (f32x4){0.f,0.f,0.f,0.f};

  for (int k0 = 0; k0 < C; k0 += BK){
    glds16(&A_lds[w*1024      ], Ap + (size_t)(srow0     )*C + k0 + scol);
    glds16(&A_lds[w*1024 + 512], Ap + (size_t)(srow0 + 16)*C + k0 + scol);
    glds16(&B_lds[w*1024      ], Bp + (size_t)(srow0     )*C + k0 + scol);
    glds16(&B_lds[w*1024 + 512], Bp + (size_t)(srow0 + 16)*C + k0 + scol);
    __syncthreads();

    bf16x8 a[4], b[4];
    #pragma unroll
    for (int mf=0; mf<4; mf++)
      a[mf] = *reinterpret_cast<const bf16x8*>(&A_lds[(wm*64 + mf*16 + l15)*BK + lq*8]);
    #pragma unroll
    for (int nf=0; nf<4; nf++)
      b[nf] = *reinterpret_cast<const bf16x8*>(&B_lds[(wn*64 + nf*16 + l15)*BK + lq*8]);
    #pragma unroll
    for (int mf=0; mf<4; mf++)
      #pragma unroll
      for (int nf=0; nf<4; nf++)
        acc[mf][nf] = __builtin_amdgcn_mfma_f32_16x16x32_bf16(a[mf], b[nf], acc[mf][nf], 0, 0, 0);
    __syncthreads();
  }

  // epilogue: out[bt][g*768+o][n] = acc + bias[g*768+o]*s[bt][g*768+o]
  #pragma unroll
  for (int nf=0; nf<4; nf++){
    int col = tn*128 + wn*64 + nf*16 + l15;
    unsigned bt = (unsigned)col / 208u;
    unsigned n  = (unsigned)col - bt*208u;
    if (n < NTOK){
      #pragma unroll
      for (int mf=0; mf<4; mf++){
        int o = tm*128 + wm*64 + mf*16 + lq*4;
        #pragma unroll
        for (int r=0; r<4; r++){
          int oo = o + r;
          float bs = bias[g*C + oo] * s_ws[(size_t)bt*C3 + g*C + oo];
          out[((size_t)bt*C3 + g*C + oo)*NTOK + n] = acc[mf][nf][r] + bs;
        }
      }
    }
  }
}

// ---------------------------------------------------------------------------
// Round-1 fallback kernels (used only if ws_size is small)
// ---------------------------------------------------------------------------
__global__ __launch_bounds__(256)
void conv_scales(const float* __restrict__ x, const float* __restrict__ aw,
                 const float* __restrict__ ab, float* __restrict__ s_ws)
{
  __shared__ __align__(16) float cls[10][C];
  __shared__ float partial[64][4][8];
  const int oc  = blockIdx.x;
  const int b   = blockIdx.y;
  const int tid = threadIdx.x;

  for (int task = tid; task < 1920; task += 256){
    int row = task / 192, c4 = task % 192;
    float4 v = {0.f,0.f,0.f,0.f};
    if (row >= 1 && row <= 8)
      v = *reinterpret_cast<const float4*>(x + (size_t)(b*8 + row - 1)*NTOK*C + c4*4);
    *reinterpret_cast<float4*>(&cls[row][c4*4]) = v;
  }
  __syncthreads();

  const int ol = tid >> 2, part = tid & 3;
  const int o_full = oc*64 + ol;
  float acc[8];
  #pragma unroll
  for (int t=0;t<8;t++) acc[t]=0.f;
  const float* awrow = aw + (size_t)o_full*C3;

  for (int i = part*192; i < part*192 + 192; i += 4){
    const float* ap = awrow + i*3;
    float4 a0 = *reinterpret_cast<const float4*>(ap);
    float4 a1 = *reinterpret_cast<const float4*>(ap+4);
    float4 a2 = *reinterpret_cast<const float4*>(ap+8);
    float awf[12] = {a0.x,a0.y,a0.z,a0.w, a1.x,a1.y,a1.z,a1.w, a2.x,a2.y,a2.z,a2.w};
    float4 cv[10];
    #pragma unroll
    for (int t=0;t<10;t++) cv[t] = *reinterpret_cast<const float4*>(&cls[t][i]);
    #pragma unroll
    for (int e=0;e<4;e++){
      float w0 = awf[e*3+0], w1 = awf[e*3+1], w2 = awf[e*3+2];
      #pragma unroll
      for (int t=0;t<8;t++){
        const float* c0 = reinterpret_cast<const float*>(&cv[t]);
        const float* c1 = reinterpret_cast<const float*>(&cv[t+1]);
        const float* c2 = reinterpret_cast<const float*>(&cv[t+2]);
        acc[t] += w0*c0[e] + w1*c1[e] + w2*c2[e];
      }
    }
  }
  #pragma unroll
  for (int t=0;t<8;t++) partial[ol][part][t] = acc[t];
  __syncthreads();

  for (int idx = tid; idx < 512; idx += 256){
    int o_l = idx >> 3, t = idx & 7;
    float v = partial[o_l][0][t] + partial[o_l][1][t]
            + partial[o_l][2][t] + partial[o_l][3][t]
            + ab[oc*64 + o_l] + 1.0f;
    s_ws[(size_t)(b*8 + t)*C3 + oc*64 + o_l] = v;
  }
}

__global__ __launch_bounds__(512)
void gemm_fallback(const float* __restrict__ x, const ushort* __restrict__ wbf,
                   const float* __restrict__ s_ws, const float* __restrict__ bias,
                   float* __restrict__ out)
{
  __shared__ __align__(16) ushort A_lds[BM*PK];
  __shared__ __align__(16) ushort B_lds[208*PK];
  const int ot  = blockIdx.x;
  const int g   = blockIdx.y;
  const int bt  = blockIdx.z;
  const int tid = threadIdx.x;
  const int w = tid >> 6, lane = tid & 63;
  const int l15 = lane & 15, lq = lane >> 4;

  const float*  srow  = s_ws + (size_t)bt*C3 + (size_t)g*C;
  const ushort* wrow  = wbf + ((size_t)g*C + (size_t)ot*BM)*C;
  const float*  xrow  = x   + (size_t)bt*NTOK*C;

  f32x4 acc[NT];
  #pragma unroll
  for (int j=0;j<NT;j++) acc[j] = (f32x4){0.f,0.f,0.f,0.f};

  const int ar = tid >> 2, ac = tid & 3;

  for (int k0 = 0; k0 < C; k0 += BK){
    {
      uint4 wv = *reinterpret_cast<const uint4*>(wrow + (size_t)ar*C + k0 + ac*8);
      const float* sv = srow + k0 + ac*8;
      float4 s0 = *reinterpret_cast<const float4*>(sv);
      float4 s1 = *reinterpret_cast<const float4*>(sv+4);
      uint4 av;
      av.x = pack2(bfu2f(wv.x & 0xffffu)*s0.x, bfu2f(wv.x >> 16)*s0.y);
      av.y = pack2(bfu2f(wv.y & 0xffffu)*s0.z, bfu2f(wv.y >> 16)*s0.w);
      av.z = pack2(bfu2f(wv.z & 0xffffu)*s1.x, bfu2f(wv.z >> 16)*s1.y);
      av.w = pack2(bfu2f(wv.w & 0xffffu)*s1.z, bfu2f(wv.w >> 16)*s1.w);
      *reinterpret_cast<uint4*>(&A_lds[ar*PK + ac*8]) = av;
    }
    #pragma unroll
    for (int it = 0; it < 2; ++it){
      int task = tid + it*512;
      if (task < 832){
        int r = task >> 2, cc = task & 3;
        uint4 bv = {0u,0u,0u,0u};
        if (r < NTOK){
          const float* p = xrow + (size_t)r*C + k0 + cc*8;
          float4 lo = *reinterpret_cast<const float4*>(p);
          float4 hi = *reinterpret_cast<const float4*>(p+4);
          bv.x = pack2(lo.x, lo.y); bv.y = pack2(lo.z, lo.w);
          bv.z = pack2(hi.x, hi.y); bv.w = pack2(hi.z, hi.w);
        }
        *reinterpret_cast<uint4*>(&B_lds[r*PK + cc*8]) = bv;
      }
    }
    __syncthreads();

    bf16x8 a = *reinterpret_cast<const bf16x8*>(&A_lds[(w*16 + l15)*PK + lq*8]);
    #pragma unroll
    for (int j=0;j<NT;j++){
      bf16x8 b = *reinterpret_cast<const bf16x8*>(&B_lds[(j*16 + l15)*PK + lq*8]);
      acc[j] = __builtin_amdgcn_mfma_f32_16x16x32_bf16(a, b, acc[j], 0, 0, 0);
    }
    __syncthreads();
  }

  const int obase = ot*BM + w*16 + lq*4;
  float bs[4];
  #pragma unroll
  for (int r=0;r<4;r++)
    bs[r] = bias[g*C + obase + r] * srow[obase + r];
  #pragma unroll
  for (int j=0;j<NT;j++){
    int n = j*16 + l15;
    if (n < NTOK){
      #pragma unroll
      for (int r=0;r<4;r++)
        out[((size_t)bt*C3 + g*C + obase + r)*NTOK + n] = acc[j][r] + bs[r];
    }
  }
}

// ---------------------------------------------------------------------------
extern "C" void kernel_launch(void* const* d_in, const int* in_sizes, int n_in,
                              void* d_out, int out_size, void* d_ws, size_t ws_size,
                              hipStream_t stream)
{
  const float* x        = (const float*)d_in[0];
  const float* a_weight = (const float*)d_in[1];
  const float* a_bias   = (const float*)d_in[2];
  const float* weight   = (const float*)d_in[3];
  const float* bias     = (const float*)d_in[4];
  float* out = (float*)d_out;

  char* ws = (char*)d_ws;
  float*  s_ws = (float*)ws;                       // 1,179,648 B
  ushort* wbf  = (ushort*)(ws + 1179648);          // 3,538,944 B
  ushort* awbf = (ushort*)(ws + 4718592);          // 10,616,832 B
  ushort* Xs   = (ushort*)(ws + 15335424);         // 122,683,392 B
  const size_t NEED_FULL = 138018816;
  const size_t NEED_MID  = 15335424;

  cvt_bf16<<<dim3(1728), 256, 0, stream>>>(weight, wbf, 442368);      // 2304*768/4

  if (ws_size >= NEED_FULL){
    cvt_bf16<<<dim3(4096), 256, 0, stream>>>(a_weight, awbf, 1327104); // 2304*2304/4
    conv_scales2<<<dim3(36,16), 256, 0, stream>>>(x, awbf, a_bias, s_ws);
    scale_x<<<dim3(2048), 256, 0, stream>>>(x, s_ws, Xs);
    gemm2<<<dim3(208,6,3), 256, 0, stream>>>(wbf, Xs, s_ws, bias, out);
  } else if (ws_size >= NEED_MID){
    cvt_bf16<<<dim3(4096), 256, 0, stream>>>(a_weight, awbf, 1327104);
    conv_scales2<<<dim3(36,16), 256, 0, stream>>>(x, awbf, a_bias, s_ws);
    gemm_fallback<<<dim3(6,3,128), 512, 0, stream>>>(x, wbf, s_ws, bias, out);
  } else {
    conv_scales<<<dim3(36,16), 256, 0, stream>>>(x, a_weight, a_bias, s_ws);
    gemm_fallback<<<dim3(6,3,128), 512, 0, stream>>>(x, wbf, s_ws, bias, out);
  }
}